// Round 4
// baseline (143.741 us; speedup 1.0000x reference)
//
#include <hip/hip_runtime.h>
#include <stdint.h>

// NormalizedLoss: batched chamfer + coverage/quality on point clouds.
// x: [32, 2048, 3] fp32, y: [32, 2048, 3] fp32 -> out: [val, cd, cov, qual] fp32.
//
// R4: R3 profile showed OccupancyPercent 15.6% (512 blocks x 4 waves = only
// 2 waves/SIMD) -> latency-stall bound at VALUBusy 64%. Fix: 512-thread
// blocks (8 waves), q split 8-way inside the block (256 q/wave), keeping
// P=4 register blocking. Same 512-block grid -> 16 waves/CU = 4 waves/SIMD.
// VALU floor ~20.5 us (268M pairs x 6 ops), LDS broadcast pipe ~20 us,
// overlapped. Assemble fused in via last-block pattern (atomic-RMW reads for
// cross-XCD coherence) -> 2 dispatches total.

#define BB 32
#define NP 2048
#define BIGF 1e10f
#define NBLK 512  // side(2) x b(32) x pc(8)

typedef unsigned int u32;

__global__ __launch_bounds__(512, 4) void nn_fused_kernel(
    const float* __restrict__ x, const float* __restrict__ y,
    u32* __restrict__ hitmask, float* __restrict__ sums,
    float* __restrict__ cnts, u32* __restrict__ counter,
    float* __restrict__ out) {
  int bid = blockIdx.x;
  int side = bid >> 8;
  int b = (bid >> 3) & 31;
  int pc = bid & 7;

  __shared__ float4 qs[NP];          // 32KB packed q: (-2q0,-2q1,-2q2, qn[+BIG])
  __shared__ float2 merged[8][256];  // 16KB per-wave (best, idx) partials
  __shared__ float pxn[256];         // ||p||^2
  __shared__ float pvalid[256];      // 1.0 if p row valid
  __shared__ int isLast;
  __shared__ float l_cd, l_cov, l_qual;

  int tid = threadIdx.x;
  // ---- stage all 2048 q of this (side,b), packed, 4 per thread ----
  const float* qraw = (side ? x : y) + b * NP * 3;
  for (int k = 0; k < 4; ++k) {
    int i = tid + 512 * k;
    float q0 = qraw[3 * i], q1 = qraw[3 * i + 1], q2 = qraw[3 * i + 2];
    float s = q0 + q1 + q2;  // invalid q row iff coord sum == 0
    float qn = q0 * q0 + q1 * q1 + q2 * q2;
    if (s == 0.0f) qn += BIGF;
    qs[i] = make_float4(-2.0f * q0, -2.0f * q1, -2.0f * q2, qn);
  }

  int w = tid >> 6, lane = tid & 63;
  // ---- every wave loads the SAME 256 p-points: p_local = lane + 64k ----
  const float* praw = (side ? y : x) + (b * NP + pc * 256) * 3;
  float p0[4], p1[4], p2[4];
  for (int k = 0; k < 4; ++k) {
    int pl = lane + 64 * k;
    p0[k] = praw[3 * pl];
    p1[k] = praw[3 * pl + 1];
    p2[k] = praw[3 * pl + 2];
    if (w == 0) {
      pxn[pl] = p0[k] * p0[k] + p1[k] * p1[k] + p2[k] * p2[k];
      pvalid[pl] = ((p0[k] + p1[k] + p2[k]) != 0.0f) ? 1.0f : 0.0f;
    }
  }
  if (tid == 0) { l_cd = 0.f; l_cov = 0.f; l_qual = 0.f; }
  __syncthreads();

  // ---- main loop: this wave's 256-q slice vs its 4 p-points ----
  float best0 = 3.0e38f, best1 = 3.0e38f, best2 = 3.0e38f, best3 = 3.0e38f;
  int bj0 = 0, bj1 = 0, bj2 = 0, bj3 = 0;
  const float4* qq = &qs[w * 256];
#pragma unroll 8
  for (int j = 0; j < 256; ++j) {
    float4 q = qq[j];  // wave-uniform broadcast, amortized over 4 pairs
    float d0 = fmaf(q.x, p0[0], fmaf(q.y, p1[0], fmaf(q.z, p2[0], q.w)));
    float d1 = fmaf(q.x, p0[1], fmaf(q.y, p1[1], fmaf(q.z, p2[1], q.w)));
    float d2 = fmaf(q.x, p0[2], fmaf(q.y, p1[2], fmaf(q.z, p2[2], q.w)));
    float d3 = fmaf(q.x, p0[3], fmaf(q.y, p1[3], fmaf(q.z, p2[3], q.w)));
    if (d0 < best0) { best0 = d0; bj0 = j; }  // strict < keeps first index
    if (d1 < best1) { best1 = d1; bj1 = j; }
    if (d2 < best2) { best2 = d2; bj2 = j; }
    if (d3 < best3) { best3 = d3; bj3 = j; }
  }
  int qoff = w * 256;
  merged[w][lane +   0] = make_float2(best0, __int_as_float(qoff + bj0));
  merged[w][lane +  64] = make_float2(best1, __int_as_float(qoff + bj1));
  merged[w][lane + 128] = make_float2(best2, __int_as_float(qoff + bj2));
  merged[w][lane + 192] = make_float2(best3, __int_as_float(qoff + bj3));
  __syncthreads();

  // ---- merge 8 partials (ascending w + strict < == first-index ties) ----
  float contrib = 0.f, cnt = 0.f;
  if (tid < 256) {
    float2 e0 = merged[0][tid];
    float bd = e0.x;
    int bi = __float_as_int(e0.y);
    for (int ww = 1; ww < 8; ++ww) {
      float2 e = merged[ww][tid];
      if (e.x < bd) { bd = e.x; bi = __float_as_int(e.y); }
    }
    float valid = pvalid[tid];
    contrib = valid * (bd + pxn[tid]);  // restore ||p||^2 term, mask invalid p
    cnt = valid;
    if (valid != 0.0f)
      atomicOr(&hitmask[(side * BB + b) * 64 + (bi >> 5)], 1u << (bi & 31));
  }
  for (int o = 32; o > 0; o >>= 1) {
    contrib += __shfl_down(contrib, o, 64);
    cnt += __shfl_down(cnt, o, 64);
  }
  if (lane == 0 && w < 4) {
    atomicAdd(&sums[side * BB + b], contrib);
    atomicAdd(&cnts[side * BB + b], cnt);
  }

  // ---- last-block assemble ----
  __threadfence();  // all prior atomics/stores visible device-wide
  __syncthreads();
  if (tid == 0) isLast = (atomicAdd(counter, 1u) == NBLK - 1);
  __syncthreads();
  if (!isLast) return;  // block-uniform

  int sb = tid >> 3, c = tid & 7;  // sb = side*32+b row, c = word chunk
  float h = 0.f;
  for (int i = 0; i < 8; ++i)  // atomic RMW read = coherent across XCDs
    h += (float)__popc(atomicOr(&hitmask[sb * 64 + c * 8 + i], 0u));
  h += __shfl_down(h, 4, 8);
  h += __shfl_down(h, 2, 8);
  h += __shfl_down(h, 1, 8);
  if (c == 0) {
    float sv = atomicAdd(&sums[sb], 0.0f);
    float cv = atomicAdd(&cnts[sb], 0.0f);
    float ocv = atomicAdd(&cnts[sb ^ 32], 0.0f);  // opposite side's count
    atomicAdd(&l_cd, sv / cv);
    if (sb < 32) atomicAdd(&l_cov, h / ocv);   // side0 hits y: /ny
    else         atomicAdd(&l_qual, h / ocv);  // side1 hits x: /nx
  }
  __syncthreads();
  if (tid == 0) {
    float cd = l_cd / (float)BB, cov = l_cov / (float)BB, qual = l_qual / (float)BB;
    out[0] = cd - 1e-4f * cov - 1e-4f * qual;  // WCD*cd - WCOV*cov - WQUAL*qual
    out[1] = cd;
    out[2] = cov;
    out[3] = qual;
  }
}

extern "C" void kernel_launch(void* const* d_in, const int* in_sizes, int n_in,
                              void* d_out, int out_size, void* d_ws, size_t ws_size,
                              hipStream_t stream) {
  const float* x = (const float*)d_in[0];
  const float* y = (const float*)d_in[1];
  float* out = (float*)d_out;
  char* ws = (char*)d_ws;

  // ws layout: [0,16KB) hitmask | +256B sums | +256B cnts | +4B counter
  u32* hitmask = (u32*)ws;
  float* sums = (float*)(ws + 16384);
  float* cnts = sums + 2 * BB;
  u32* counter = (u32*)(cnts + 2 * BB);

  hipMemsetAsync(ws, 0, 16384 + 512 + 4, stream);
  nn_fused_kernel<<<NBLK, 512, 0, stream>>>(x, y, hitmask, sums, cnts, counter, out);
}

// Round 5
// 103.034 us; speedup vs baseline: 1.3951x; 1.3951x over previous
//
#include <hip/hip_runtime.h>
#include <stdint.h>

// NormalizedLoss: batched chamfer + coverage/quality on point clouds.
// x: [32, 2048, 3] fp32, y: [32, 2048, 3] fp32 -> out: [val, cd, cov, qual] fp32.
//
// R5: R4 regressed (50->93 us) from two causes visible in counters:
//  (1) __launch_bounds__(512,4) forced VGPR 68->40 -> compiler couldn't keep
//      unroll-8 ds_reads in flight -> lgkmcnt stall per iter (VALUBusy 64->37)
//  (2) fused last-block epilogue: __threadfence (device-release = L2 writeback
//      on non-coherent XCDs) + counter atomic x 512 blocks.
// Fix: keep the 8-wave / P=4 shape (16 waves/CU = 4/SIMD; LDS pipe only
// ~11 us at P=4 per back-solved 6.5 cyc/broadcast-b128), but default launch
// bounds (VGPR floats to ~70-84, still 4 waves/SIMD) and a separate 1-wave
// assemble kernel. VALU floor ~22.5 us.

#define BB 32
#define NP 2048
#define BIGF 1e10f

typedef unsigned int u32;

__global__ __launch_bounds__(512) void nn_fused_kernel(
    const float* __restrict__ x, const float* __restrict__ y,
    u32* __restrict__ hitmask, float* __restrict__ sums,
    float* __restrict__ cnts) {
  int bid = blockIdx.x;  // 512 blocks: side(2) x b(32) x pc(8)
  int side = bid >> 8;
  int b = (bid >> 3) & 31;
  int pc = bid & 7;

  __shared__ float4 qs[NP];          // 32KB packed q: (-2q0,-2q1,-2q2, qn[+BIG])
  __shared__ float2 merged[8][256];  // 16KB per-wave (best, idx) partials
  __shared__ float pxn[256];         // ||p||^2
  __shared__ float pvalid[256];      // 1.0 if p row valid

  int tid = threadIdx.x;
  // ---- stage all 2048 q of this (side,b), packed, 4 per thread ----
  const float* qraw = (side ? x : y) + b * NP * 3;
  for (int k = 0; k < 4; ++k) {
    int i = tid + 512 * k;
    float q0 = qraw[3 * i], q1 = qraw[3 * i + 1], q2 = qraw[3 * i + 2];
    float s = q0 + q1 + q2;  // invalid q row iff coord sum == 0
    float qn = q0 * q0 + q1 * q1 + q2 * q2;
    if (s == 0.0f) qn += BIGF;
    qs[i] = make_float4(-2.0f * q0, -2.0f * q1, -2.0f * q2, qn);
  }

  int w = tid >> 6, lane = tid & 63;
  // ---- every wave loads the SAME 256 p-points: p_local = lane + 64k ----
  const float* praw = (side ? y : x) + (b * NP + pc * 256) * 3;
  float p0[4], p1[4], p2[4];
  for (int k = 0; k < 4; ++k) {
    int pl = lane + 64 * k;
    p0[k] = praw[3 * pl];
    p1[k] = praw[3 * pl + 1];
    p2[k] = praw[3 * pl + 2];
    if (w == 0) {
      pxn[pl] = p0[k] * p0[k] + p1[k] * p1[k] + p2[k] * p2[k];
      pvalid[pl] = ((p0[k] + p1[k] + p2[k]) != 0.0f) ? 1.0f : 0.0f;
    }
  }
  __syncthreads();

  // ---- main loop: this wave's 256-q slice vs its 4 p-points ----
  float best0 = 3.0e38f, best1 = 3.0e38f, best2 = 3.0e38f, best3 = 3.0e38f;
  int bj0 = 0, bj1 = 0, bj2 = 0, bj3 = 0;
  const float4* qq = &qs[w * 256];
#pragma unroll 8
  for (int j = 0; j < 256; ++j) {
    float4 q = qq[j];  // wave-uniform broadcast, amortized over 4 pairs
    float d0 = fmaf(q.x, p0[0], fmaf(q.y, p1[0], fmaf(q.z, p2[0], q.w)));
    float d1 = fmaf(q.x, p0[1], fmaf(q.y, p1[1], fmaf(q.z, p2[1], q.w)));
    float d2 = fmaf(q.x, p0[2], fmaf(q.y, p1[2], fmaf(q.z, p2[2], q.w)));
    float d3 = fmaf(q.x, p0[3], fmaf(q.y, p1[3], fmaf(q.z, p2[3], q.w)));
    if (d0 < best0) { best0 = d0; bj0 = j; }  // strict < keeps first index
    if (d1 < best1) { best1 = d1; bj1 = j; }
    if (d2 < best2) { best2 = d2; bj2 = j; }
    if (d3 < best3) { best3 = d3; bj3 = j; }
  }
  int qoff = w * 256;
  merged[w][lane +   0] = make_float2(best0, __int_as_float(qoff + bj0));
  merged[w][lane +  64] = make_float2(best1, __int_as_float(qoff + bj1));
  merged[w][lane + 128] = make_float2(best2, __int_as_float(qoff + bj2));
  merged[w][lane + 192] = make_float2(best3, __int_as_float(qoff + bj3));
  __syncthreads();

  // ---- merge 8 partials (ascending w + strict < == first-index ties) ----
  float contrib = 0.f, cnt = 0.f;
  if (tid < 256) {
    float2 e0 = merged[0][tid];
    float bd = e0.x;
    int bi = __float_as_int(e0.y);
    for (int ww = 1; ww < 8; ++ww) {
      float2 e = merged[ww][tid];
      if (e.x < bd) { bd = e.x; bi = __float_as_int(e.y); }
    }
    float valid = pvalid[tid];
    contrib = valid * (bd + pxn[tid]);  // restore ||p||^2 term, mask invalid p
    cnt = valid;
    if (valid != 0.0f)
      atomicOr(&hitmask[(side * BB + b) * 64 + (bi >> 5)], 1u << (bi & 31));
  }
  for (int o = 32; o > 0; o >>= 1) {
    contrib += __shfl_down(contrib, o, 64);
    cnt += __shfl_down(cnt, o, 64);
  }
  if (lane == 0 && w < 4) {  // waves 4..7 carry zero contrib
    atomicAdd(&sums[side * BB + b], contrib);
    atomicAdd(&cnts[side * BB + b], cnt);
  }
}

// Single wave: lanes 0..31 each assemble one batch; shuffle-reduce; write 4.
__global__ __launch_bounds__(64) void assemble_kernel(const u32* __restrict__ hitmask,
                                                      const float* __restrict__ sums,
                                                      const float* __restrict__ cnts,
                                                      float* __restrict__ out) {
  int t = threadIdx.x;
  float cd = 0.f, cov = 0.f, qual = 0.f;
  if (t < BB) {
    float nx = cnts[t], ny = cnts[BB + t];
    int hy = 0, hx = 0;
    for (int i = 0; i < 64; ++i) hy += __popc(hitmask[t * 64 + i]);          // side0 hits y
    for (int i = 0; i < 64; ++i) hx += __popc(hitmask[(BB + t) * 64 + i]);   // side1 hits x
    cd = sums[t] / nx + sums[BB + t] / ny;
    cov = (float)hy / ny;
    qual = (float)hx / nx;
  }
  for (int o = 32; o > 0; o >>= 1) {
    cd += __shfl_down(cd, o, 64);
    cov += __shfl_down(cov, o, 64);
    qual += __shfl_down(qual, o, 64);
  }
  if (t == 0) {
    cd /= (float)BB; cov /= (float)BB; qual /= (float)BB;
    out[0] = cd - 1e-4f * cov - 1e-4f * qual;  // WCD*cd - WCOV*cov - WQUAL*qual
    out[1] = cd;
    out[2] = cov;
    out[3] = qual;
  }
}

extern "C" void kernel_launch(void* const* d_in, const int* in_sizes, int n_in,
                              void* d_out, int out_size, void* d_ws, size_t ws_size,
                              hipStream_t stream) {
  const float* x = (const float*)d_in[0];
  const float* y = (const float*)d_in[1];
  float* out = (float*)d_out;
  char* ws = (char*)d_ws;

  // ws layout: [0,16KB) hitmask (2*32 batches x 64 u32 words) | +256B sums | +256B cnts
  u32* hitmask = (u32*)ws;
  float* sums = (float*)(ws + 16384);
  float* cnts = sums + 2 * BB;

  hipMemsetAsync(ws, 0, 16384 + 512, stream);
  nn_fused_kernel<<<2 * BB * 8, 512, 0, stream>>>(x, y, hitmask, sums, cnts);
  assemble_kernel<<<1, 64, 0, stream>>>(hitmask, sums, cnts, out);
}

// Round 6
// 91.751 us; speedup vs baseline: 1.5666x; 1.1230x over previous
//
#include <hip/hip_runtime.h>
#include <stdint.h>

// NormalizedLoss: batched chamfer + coverage/quality on point clouds.
// x: [32, 2048, 3] fp32, y: [32, 2048, 3] fp32 -> out: [val, cd, cov, qual] fp32.
//
// R6: R5 sat at 51 us, VALUBusy 65%, VGPR 40 -> only ~2 in-flight q loads,
// lgkmcnt stall every ~2 iters. Changes:
//  (a) explicit 2-deep software pipeline (rotating 4x float4 groups) so >=8
//      ds_reads stay outstanding -- live ranges force the VGPRs the heuristic
//      wouldn't allocate;
//  (b) index-in-mantissa argmin: d_trunc = (bits(d) & ~0x7FF) | j_global
//      (j fits 11 bits exactly), single v_min_f32 per pair -> 6 VALU/pair,
//      no index regs, merged[] halves to u32. Truncation error ~1e-3 << 1.2e-2
//      threshold; tie-break flips only among 2^-11 near-ties (cov/qual noise).

#define BB 32
#define NP 2048
#define BIGF 1e10f

typedef unsigned int u32;

__device__ __forceinline__ float emb_min(float best, float d, u32 jg) {
  u32 bits = (__float_as_uint(d) & 0xFFFFF800u) | jg;
  return fminf(best, __uint_as_float(bits));
}

__global__ __launch_bounds__(512) void nn_fused_kernel(
    const float* __restrict__ x, const float* __restrict__ y,
    u32* __restrict__ hitmask, float* __restrict__ sums,
    float* __restrict__ cnts) {
  int bid = blockIdx.x;  // 512 blocks: side(2) x b(32) x pc(8)
  int side = bid >> 8;
  int b = (bid >> 3) & 31;
  int pc = bid & 7;

  __shared__ float4 qs[NP + 8];    // +8 pad: pipeline prologue reads 4 past end
  __shared__ u32 merged[8][256];   // 8KB per-wave embedded (d|idx) partials
  __shared__ float pxn[256];       // ||p||^2
  __shared__ float pvalid[256];    // 1.0 if p row valid

  int tid = threadIdx.x;
  // ---- stage all 2048 q of this (side,b), packed, 4 per thread ----
  const float* qraw = (side ? x : y) + b * NP * 3;
  for (int k = 0; k < 4; ++k) {
    int i = tid + 512 * k;
    float q0 = qraw[3 * i], q1 = qraw[3 * i + 1], q2 = qraw[3 * i + 2];
    float s = q0 + q1 + q2;  // invalid q row iff coord sum == 0
    float qn = q0 * q0 + q1 * q1 + q2 * q2;
    if (s == 0.0f) qn += BIGF;  // push invalid q out of every min
    qs[i] = make_float4(-2.0f * q0, -2.0f * q1, -2.0f * q2, qn);
  }

  int w = tid >> 6, lane = tid & 63;
  // ---- every wave loads the SAME 256 p-points: p_local = lane + 64k ----
  const float* praw = (side ? y : x) + (b * NP + pc * 256) * 3;
  float p0[4], p1[4], p2[4];
  for (int k = 0; k < 4; ++k) {
    int pl = lane + 64 * k;
    p0[k] = praw[3 * pl];
    p1[k] = praw[3 * pl + 1];
    p2[k] = praw[3 * pl + 2];
    if (w == 0) {
      pxn[pl] = p0[k] * p0[k] + p1[k] * p1[k] + p2[k] * p2[k];
      pvalid[pl] = ((p0[k] + p1[k] + p2[k]) != 0.0f) ? 1.0f : 0.0f;
    }
  }
  __syncthreads();

  // ---- main loop: this wave's 256-q slice vs its 4 p-points ----
  // 2-deep software pipeline: while PROCessing group A, group B is in regs
  // and group A' of the next pass is in flight (>=8 outstanding ds_reads).
  float best0 = 3.0e38f, best1 = 3.0e38f, best2 = 3.0e38f, best3 = 3.0e38f;
  const float4* qq = &qs[w * 256];
  u32 qoff = (u32)(w * 256);

#define PROC(q, jg)                                                              \
  {                                                                              \
    float d0 = fmaf((q).x, p0[0], fmaf((q).y, p1[0], fmaf((q).z, p2[0], (q).w))); \
    float d1 = fmaf((q).x, p0[1], fmaf((q).y, p1[1], fmaf((q).z, p2[1], (q).w))); \
    float d2 = fmaf((q).x, p0[2], fmaf((q).y, p1[2], fmaf((q).z, p2[2], (q).w))); \
    float d3 = fmaf((q).x, p0[3], fmaf((q).y, p1[3], fmaf((q).z, p2[3], (q).w))); \
    best0 = emb_min(best0, d0, (jg));                                            \
    best1 = emb_min(best1, d1, (jg));                                            \
    best2 = emb_min(best2, d2, (jg));                                            \
    best3 = emb_min(best3, d3, (jg));                                            \
  }

  float4 qa0 = qq[0], qa1 = qq[1], qa2 = qq[2], qa3 = qq[3];
  for (int jc = 0; jc < 256; jc += 8) {
    float4 qb0 = qq[jc + 4], qb1 = qq[jc + 5], qb2 = qq[jc + 6], qb3 = qq[jc + 7];
    u32 jg = qoff + (u32)jc;
    PROC(qa0, jg);     PROC(qa1, jg + 1); PROC(qa2, jg + 2); PROC(qa3, jg + 3);
    qa0 = qq[jc + 8];  qa1 = qq[jc + 9];  qa2 = qq[jc + 10]; qa3 = qq[jc + 11];
    PROC(qb0, jg + 4); PROC(qb1, jg + 5); PROC(qb2, jg + 6); PROC(qb3, jg + 7);
  }
  // final qa group (jc=256..259) is pad garbage, never PROCessed.

  merged[w][lane +   0] = __float_as_uint(best0);
  merged[w][lane +  64] = __float_as_uint(best1);
  merged[w][lane + 128] = __float_as_uint(best2);
  merged[w][lane + 192] = __float_as_uint(best3);
  __syncthreads();

  // ---- merge 8 partials: fminf on embedded values = (d,idx) lexicographic ----
  float contrib = 0.f, cnt = 0.f;
  if (tid < 256) {
    float bd = __uint_as_float(merged[0][tid]);
    for (int ww = 1; ww < 8; ++ww)
      bd = fminf(bd, __uint_as_float(merged[ww][tid]));
    u32 bits = __float_as_uint(bd);
    u32 bi = bits & 0x7FFu;                              // global q index
    float dmin = __uint_as_float(bits & 0xFFFFF800u);    // truncated min d'
    float valid = pvalid[tid];
    contrib = valid * (dmin + pxn[tid]);  // restore ||p||^2 term, mask invalid
    cnt = valid;
    if (valid != 0.0f)
      atomicOr(&hitmask[(side * BB + b) * 64 + (bi >> 5)], 1u << (bi & 31));
  }
  for (int o = 32; o > 0; o >>= 1) {
    contrib += __shfl_down(contrib, o, 64);
    cnt += __shfl_down(cnt, o, 64);
  }
  if (lane == 0 && w < 4) {  // waves 4..7 carry zero contrib
    atomicAdd(&sums[side * BB + b], contrib);
    atomicAdd(&cnts[side * BB + b], cnt);
  }
}

// Single wave: lanes 0..31 each assemble one batch; shuffle-reduce; write 4.
__global__ __launch_bounds__(64) void assemble_kernel(const u32* __restrict__ hitmask,
                                                      const float* __restrict__ sums,
                                                      const float* __restrict__ cnts,
                                                      float* __restrict__ out) {
  int t = threadIdx.x;
  float cd = 0.f, cov = 0.f, qual = 0.f;
  if (t < BB) {
    float nx = cnts[t], ny = cnts[BB + t];
    int hy = 0, hx = 0;
    for (int i = 0; i < 64; ++i) hy += __popc(hitmask[t * 64 + i]);          // side0 hits y
    for (int i = 0; i < 64; ++i) hx += __popc(hitmask[(BB + t) * 64 + i]);   // side1 hits x
    cd = sums[t] / nx + sums[BB + t] / ny;
    cov = (float)hy / ny;
    qual = (float)hx / nx;
  }
  for (int o = 32; o > 0; o >>= 1) {
    cd += __shfl_down(cd, o, 64);
    cov += __shfl_down(cov, o, 64);
    qual += __shfl_down(qual, o, 64);
  }
  if (t == 0) {
    cd /= (float)BB; cov /= (float)BB; qual /= (float)BB;
    out[0] = cd - 1e-4f * cov - 1e-4f * qual;  // WCD*cd - WCOV*cov - WQUAL*qual
    out[1] = cd;
    out[2] = cov;
    out[3] = qual;
  }
}

extern "C" void kernel_launch(void* const* d_in, const int* in_sizes, int n_in,
                              void* d_out, int out_size, void* d_ws, size_t ws_size,
                              hipStream_t stream) {
  const float* x = (const float*)d_in[0];
  const float* y = (const float*)d_in[1];
  float* out = (float*)d_out;
  char* ws = (char*)d_ws;

  // ws layout: [0,16KB) hitmask (2*32 batches x 64 u32 words) | +256B sums | +256B cnts
  u32* hitmask = (u32*)ws;
  float* sums = (float*)(ws + 16384);
  float* cnts = sums + 2 * BB;

  hipMemsetAsync(ws, 0, 16384 + 512, stream);
  nn_fused_kernel<<<2 * BB * 8, 512, 0, stream>>>(x, y, hitmask, sums, cnts);
  assemble_kernel<<<1, 64, 0, stream>>>(hitmask, sums, cnts, out);
}